// Round 3
// baseline (487.818 us; speedup 1.0000x reference)
//
#include <hip/hip_runtime.h>

#define B_ 2
#define S_ 2048
#define D_ 512
#define H_ 8
#define DH_ 64

typedef __bf16 bf16_8 __attribute__((ext_vector_type(8)));
typedef float f32x4 __attribute__((ext_vector_type(4)));
typedef unsigned int u32x4 __attribute__((ext_vector_type(4)));

union BfPack4 { ushort4 u; __bf16 h[4]; };

// ---------------------------------------------------------------------------
// Kernel 1: QKV projection.  y = x @ W^T  (torch Linear), bf16 outputs.
// z=0: Q (scaled by 1/8), z=1: K, z=2: V stored transposed [B,H,DH,S].
// T14 staging split: global loads for chunk t+1 issued before compute on t.
// ---------------------------------------------------------------------------
__global__ __launch_bounds__(256) void proj_qkv(
    const float* __restrict__ Xq, const float* __restrict__ Xk, const float* __restrict__ Xv,
    const float* __restrict__ Wq, const float* __restrict__ Wk, const float* __restrict__ Wv,
    __bf16* __restrict__ Qb, __bf16* __restrict__ Kb, __bf16* __restrict__ Vt)
{
    const int z = blockIdx.z;
    const float* X = (z == 0) ? Xq : (z == 1) ? Xk : Xv;
    const float* W = (z == 0) ? Wq : (z == 1) ? Wk : Wv;
    const int m0 = blockIdx.x * 64;   // 0..4095
    const int n0 = blockIdx.y * 64;   // 0..511

    __shared__ __bf16 Xs[64][72];
    __shared__ __bf16 Ws[64][72];

    const int tid = threadIdx.x;
    const int w = tid >> 6, lane = tid & 63;
    const int quad = lane >> 4, mc = lane & 15;

    int rr[4], cc[4];
    for (int i = 0; i < 4; ++i) { int e = tid + i * 256; rr[i] = e >> 4; cc[i] = (e & 15) * 4; }

    f32x4 acc[4] = {};
    float4 xr[4], wv[4];
    for (int i = 0; i < 4; ++i) {
        xr[i] = *reinterpret_cast<const float4*>(&X[(size_t)(m0 + rr[i]) * 512 + cc[i]]);
        wv[i] = *reinterpret_cast<const float4*>(&W[(size_t)(n0 + rr[i]) * 512 + cc[i]]);
    }

    for (int kc = 0; kc < 512; kc += 64) {
        if (kc) __syncthreads();
        for (int i = 0; i < 4; ++i) {
            BfPack4 px, pw;
            px.h[0] = (__bf16)xr[i].x; px.h[1] = (__bf16)xr[i].y;
            px.h[2] = (__bf16)xr[i].z; px.h[3] = (__bf16)xr[i].w;
            *reinterpret_cast<ushort4*>(&Xs[rr[i]][cc[i]]) = px.u;
            pw.h[0] = (__bf16)wv[i].x; pw.h[1] = (__bf16)wv[i].y;
            pw.h[2] = (__bf16)wv[i].z; pw.h[3] = (__bf16)wv[i].w;
            *reinterpret_cast<ushort4*>(&Ws[rr[i]][cc[i]]) = pw.u;
        }
        __syncthreads();
        if (kc < 448) {
            for (int i = 0; i < 4; ++i) {
                xr[i] = *reinterpret_cast<const float4*>(&X[(size_t)(m0 + rr[i]) * 512 + kc + 64 + cc[i]]);
                wv[i] = *reinterpret_cast<const float4*>(&W[(size_t)(n0 + rr[i]) * 512 + kc + 64 + cc[i]]);
            }
        }
        for (int ks = 0; ks < 64; ks += 32) {
            bf16_8 a = *reinterpret_cast<const bf16_8*>(&Xs[w * 16 + mc][ks + quad * 8]);
            for (int tt = 0; tt < 4; ++tt) {
                bf16_8 bb = *reinterpret_cast<const bf16_8*>(&Ws[tt * 16 + mc][ks + quad * 8]);
                acc[tt] = __builtin_amdgcn_mfma_f32_16x16x32_bf16(a, bb, acc[tt], 0, 0, 0);
            }
        }
    }
    __syncthreads();
    // Epilogue via LDS (reuse Xs) for coalesced bf16 stores.
    const float scale = (z == 0) ? 0.125f : 1.0f;   // DH^-0.5 folded into Q
    if (z < 2) {
        for (int tt = 0; tt < 4; ++tt)
            for (int r = 0; r < 4; ++r)
                Xs[w * 16 + quad * 4 + r][tt * 16 + mc] = (__bf16)(acc[tt][r] * scale);
    } else {
        for (int tt = 0; tt < 4; ++tt)
            for (int r = 0; r < 4; ++r)
                Xs[tt * 16 + mc][w * 16 + quad * 4 + r] = (__bf16)acc[tt][r];  // transposed tile [dh][s]
    }
    __syncthreads();
    if (z < 2) {
        __bf16* out = (z == 0) ? Qb : Kb;
        for (int i = 0; i < 2; ++i) {
            int e = tid + i * 256;
            int r = e >> 3, c8 = (e & 7) * 8;
            *reinterpret_cast<uint4*>(&out[(size_t)(m0 + r) * 512 + n0 + c8]) =
                *reinterpret_cast<const uint4*>(&Xs[r][c8]);
        }
    } else {
        int b = m0 >> 11, s0 = m0 & 2047, h = n0 >> 6;
        for (int i = 0; i < 2; ++i) {
            int e = tid + i * 256;
            int r = e >> 3, c8 = (e & 7) * 8;   // r = dh, c8 = s offset
            *reinterpret_cast<uint4*>(&Vt[(((size_t)(b * H_ + h)) * DH_ + r) * S_ + s0 + c8]) =
                *reinterpret_cast<const uint4*>(&Xs[r][c8]);
        }
    }
}

// ---------------------------------------------------------------------------
// Kernel 2: single-pass attention with deferred normalization.
// One WG = (b,h) x 64 q-rows, K-chunk = 128, 16 chunks, 2 barriers each.
// Per chunk: QK -> p = exp(s) (no-max; scores bounded, exp fits fp32) ->
// stage p in LDS -> write UNNORMALIZED p (bf16, NT) to workspace ->
// PV-accumulate.  End: l complete -> Ctx = o/l, store 1/l for rescale.
// ---------------------------------------------------------------------------
__global__ __launch_bounds__(256) void attn_kernel(
    const __bf16* __restrict__ Qb, const __bf16* __restrict__ Kb, const __bf16* __restrict__ Vt,
    __bf16* __restrict__ Ctx, __bf16* __restrict__ Pws, float* __restrict__ Linv)
{
    const int qt = blockIdx.x;        // 0..31
    const int bh = blockIdx.y;        // 0..15
    const int b = bh >> 3, h = bh & 7;
    const int q0 = qt * 64;

    __shared__ __bf16 Qs[64][72];     // 9.2 KB
    __shared__ __bf16 Ks[128][72];    // 18.4 KB
    __shared__ __bf16 Ps[64][136];    // 17.4 KB
    __shared__ __bf16 Vs[64][136];    // 17.4 KB  [dh][k] (transposed chunk)

    const int tid = threadIdx.x;
    const int w = tid >> 6, lane = tid & 63;
    const int quad = lane >> 4, mc = lane & 15;

    for (int i = 0; i < 2; ++i) {
        int e = tid + i * 256;
        int r = e >> 3, c8 = (e & 7) * 8;
        *reinterpret_cast<uint4*>(&Qs[r][c8]) =
            *reinterpret_cast<const uint4*>(&Qb[((size_t)b * S_ + q0 + r) * D_ + h * DH_ + c8]);
    }
    __syncthreads();
    const bf16_8 aq0 = *reinterpret_cast<const bf16_8*>(&Qs[w * 16 + mc][quad * 8]);
    const bf16_8 aq1 = *reinterpret_cast<const bf16_8*>(&Qs[w * 16 + mc][32 + quad * 8]);

    // staging coords: K tile 128x64 (4 x uint4 / thread), V tile 64x128
    int kr[4], kcc[4], vr[4], vc[4];
    for (int i = 0; i < 4; ++i) {
        int e = tid + i * 256;
        kr[i] = e >> 3; kcc[i] = (e & 7) * 8;
        vr[i] = e >> 4; vc[i]  = (e & 15) * 8;
    }
    const __bf16* kp = Kb + (size_t)b * S_ * D_ + h * DH_;
    const __bf16* vp = Vt + (size_t)bh * DH_ * S_;

    uint4 kreg[4], vreg[4];
    for (int i = 0; i < 4; ++i) {
        kreg[i] = *reinterpret_cast<const uint4*>(&kp[(size_t)kr[i] * D_ + kcc[i]]);
        vreg[i] = *reinterpret_cast<const uint4*>(&vp[(size_t)vr[i] * S_ + vc[i]]);
    }

    float l[4] = {0.f, 0.f, 0.f, 0.f};
    f32x4 o[4] = {};

    for (int tc = 0; tc < 16; ++tc) {
        if (tc) __syncthreads();
        for (int i = 0; i < 4; ++i) {
            *reinterpret_cast<uint4*>(&Ks[kr[i]][kcc[i]]) = kreg[i];
            *reinterpret_cast<uint4*>(&Vs[vr[i]][vc[i]]) = vreg[i];
        }
        __syncthreads();
        if (tc < 15) {
            for (int i = 0; i < 4; ++i) {
                kreg[i] = *reinterpret_cast<const uint4*>(
                    &kp[(size_t)((tc + 1) * 128 + kr[i]) * D_ + kcc[i]]);
                vreg[i] = *reinterpret_cast<const uint4*>(
                    &vp[(size_t)vr[i] * S_ + (tc + 1) * 128 + vc[i]]);
            }
        }
        f32x4 s[8] = {};
        for (int ct = 0; ct < 8; ++ct) {
            bf16_8 b0 = *reinterpret_cast<const bf16_8*>(&Ks[ct * 16 + mc][quad * 8]);
            s[ct] = __builtin_amdgcn_mfma_f32_16x16x32_bf16(aq0, b0, s[ct], 0, 0, 0);
        }
        for (int ct = 0; ct < 8; ++ct) {
            bf16_8 b1 = *reinterpret_cast<const bf16_8*>(&Ks[ct * 16 + mc][32 + quad * 8]);
            s[ct] = __builtin_amdgcn_mfma_f32_16x16x32_bf16(aq1, b1, s[ct], 0, 0, 0);
        }
        // p = exp(s): lane-local l accumulation (one shuffle reduce at end),
        // stage p into Ps (wave-private rows; no barrier needed)
        for (int ct = 0; ct < 8; ++ct)
            for (int r = 0; r < 4; ++r) {
                float p = __expf(s[ct][r]);
                l[r] += p;
                Ps[w * 16 + quad * 4 + r][ct * 16 + mc] = (__bf16)p;
            }
        // unnormalized p -> workspace (bf16, NT): wave w covers its 16 rows
        const int kc = tc * 128;
        for (int i = 0; i < 4; ++i) {
            int r = w * 16 + i * 4 + quad;
            u32x4 pu = *reinterpret_cast<const u32x4*>(&Ps[r][mc * 8]);
            __builtin_nontemporal_store(pu, reinterpret_cast<u32x4*>(
                &Pws[((size_t)bh * S_ + q0 + r) * S_ + kc + mc * 8]));
        }
        // PV: A = Ps (own rows), B = Vs[dh][k]
        for (int ks = 0; ks < 128; ks += 32) {
            bf16_8 ap = *reinterpret_cast<const bf16_8*>(&Ps[w * 16 + mc][ks + quad * 8]);
            for (int tt = 0; tt < 4; ++tt) {
                bf16_8 bv = *reinterpret_cast<const bf16_8*>(&Vs[tt * 16 + mc][ks + quad * 8]);
                o[tt] = __builtin_amdgcn_mfma_f32_16x16x32_bf16(ap, bv, o[tt], 0, 0, 0);
            }
        }
    }
    // finalize denominators: reduce across the 16 mc lanes (columns)
    for (int r = 0; r < 4; ++r)
        for (int off = 1; off < 16; off <<= 1) l[r] += __shfl_xor(l[r], off);
    float linv[4];
    for (int r = 0; r < 4; ++r) linv[r] = 1.f / l[r];
    if (mc == 0)
        for (int r = 0; r < 4; ++r)
            Linv[(size_t)bh * S_ + q0 + w * 16 + quad * 4 + r] = linv[r];

    // context epilogue via LDS (reuse Qs), normalized
    __syncthreads();
    for (int tt = 0; tt < 4; ++tt)
        for (int r = 0; r < 4; ++r)
            Qs[w * 16 + quad * 4 + r][tt * 16 + mc] = (__bf16)(o[tt][r] * linv[r]);
    __syncthreads();
    for (int i = 0; i < 2; ++i) {
        int e = tid + i * 256;
        int r = e >> 3, c8 = (e & 7) * 8;
        *reinterpret_cast<uint4*>(&Ctx[((size_t)b * S_ + q0 + r) * D_ + h * DH_ + c8]) =
            *reinterpret_cast<const uint4*>(&Qs[r][c8]);
    }
}

// ---------------------------------------------------------------------------
// Kernel 2b: attention rescale.  attn_out[row,c] = f32(p[row,c]) * linv[row].
// Pure streaming: one block per row (2048 cols / 256 thr = 8 elems each),
// NT load + NT store, fully latency-tolerant.
// ---------------------------------------------------------------------------
__global__ __launch_bounds__(256) void rescale_kernel(
    const __bf16* __restrict__ Pws, const float* __restrict__ Linv,
    float* __restrict__ attn_out)
{
    const int row = blockIdx.x;                 // 0..32767 (= bh*2048 + q)
    const float s = Linv[row];
    const int c = threadIdx.x * 8;
    const size_t base = (size_t)row * S_ + c;
    u32x4 pu = __builtin_nontemporal_load(reinterpret_cast<const u32x4*>(&Pws[base]));
    const __bf16* p = reinterpret_cast<const __bf16*>(&pu);
    f32x4 lo, hi;
    for (int j = 0; j < 4; ++j) {
        lo[j] = (float)p[j] * s;
        hi[j] = (float)p[j + 4] * s;
    }
    float* dst = &attn_out[base];
    __builtin_nontemporal_store(lo, reinterpret_cast<f32x4*>(dst));
    __builtin_nontemporal_store(hi, reinterpret_cast<f32x4*>(dst + 4));
}

// ---------------------------------------------------------------------------
// Kernel 3a: output projection + bias + residual -> fp32 ws
// ---------------------------------------------------------------------------
__global__ __launch_bounds__(256) void oproj(
    const __bf16* __restrict__ Ctx, const float* __restrict__ Wo,
    const float* __restrict__ bo, const float* __restrict__ resid,
    float* __restrict__ Y)
{
    const int m0 = blockIdx.x * 64;
    const int n0 = blockIdx.y * 64;

    __shared__ __bf16 As[64][72];
    __shared__ __bf16 Bs[64][72];

    const int tid = threadIdx.x;
    const int w = tid >> 6, lane = tid & 63;
    const int quad = lane >> 4, mc = lane & 15;

    int ar[2], ac[2], wr2[4], wc2[4];
    for (int i = 0; i < 2; ++i) { int e = tid + i * 256; ar[i] = e >> 3; ac[i] = (e & 7) * 8; }
    for (int i = 0; i < 4; ++i) { int e = tid + i * 256; wr2[i] = e >> 4; wc2[i] = (e & 15) * 4; }

    uint4 areg[2];
    float4 wreg[4];
    for (int i = 0; i < 2; ++i)
        areg[i] = *reinterpret_cast<const uint4*>(&Ctx[(size_t)(m0 + ar[i]) * 512 + ac[i]]);
    for (int i = 0; i < 4; ++i)
        wreg[i] = *reinterpret_cast<const float4*>(&Wo[(size_t)(n0 + wr2[i]) * 512 + wc2[i]]);

    f32x4 acc[4] = {};
    for (int kc = 0; kc < 512; kc += 64) {
        if (kc) __syncthreads();
        for (int i = 0; i < 2; ++i)
            *reinterpret_cast<uint4*>(&As[ar[i]][ac[i]]) = areg[i];
        for (int i = 0; i < 4; ++i) {
            BfPack4 pw;
            pw.h[0] = (__bf16)wreg[i].x; pw.h[1] = (__bf16)wreg[i].y;
            pw.h[2] = (__bf16)wreg[i].z; pw.h[3] = (__bf16)wreg[i].w;
            *reinterpret_cast<ushort4*>(&Bs[wr2[i]][wc2[i]]) = pw.u;
        }
        __syncthreads();
        if (kc < 448) {
            for (int i = 0; i < 2; ++i)
                areg[i] = *reinterpret_cast<const uint4*>(&Ctx[(size_t)(m0 + ar[i]) * 512 + kc + 64 + ac[i]]);
            for (int i = 0; i < 4; ++i)
                wreg[i] = *reinterpret_cast<const float4*>(&Wo[(size_t)(n0 + wr2[i]) * 512 + kc + 64 + wc2[i]]);
        }
        for (int ks = 0; ks < 64; ks += 32) {
            bf16_8 a = *reinterpret_cast<const bf16_8*>(&As[w * 16 + mc][ks + quad * 8]);
            for (int tt = 0; tt < 4; ++tt) {
                bf16_8 bb = *reinterpret_cast<const bf16_8*>(&Bs[tt * 16 + mc][ks + quad * 8]);
                acc[tt] = __builtin_amdgcn_mfma_f32_16x16x32_bf16(a, bb, acc[tt], 0, 0, 0);
            }
        }
    }
    for (int tt = 0; tt < 4; ++tt) {
        int col = n0 + tt * 16 + mc;
        float bias = bo[col];
        for (int r = 0; r < 4; ++r) {
            int row = m0 + w * 16 + quad * 4 + r;
            Y[(size_t)row * 512 + col] = acc[tt][r] + bias + resid[(size_t)row * 512 + col];
        }
    }
}

// ---------------------------------------------------------------------------
// Kernel 3b: LayerNorm over last dim (512). One wave per row.
// ---------------------------------------------------------------------------
__global__ __launch_bounds__(256) void ln_kernel(
    const float* __restrict__ Y, const float* __restrict__ gamma,
    const float* __restrict__ beta, float* __restrict__ out)
{
    const int row = blockIdx.x * 4 + (threadIdx.x >> 6);
    const int lane = threadIdx.x & 63;
    const float* y = &Y[(size_t)row * 512];
    float4 v0 = *reinterpret_cast<const float4*>(&y[lane * 8]);
    float4 v1 = *reinterpret_cast<const float4*>(&y[lane * 8 + 4]);
    float sum = v0.x + v0.y + v0.z + v0.w + v1.x + v1.y + v1.z + v1.w;
    float sq = v0.x * v0.x + v0.y * v0.y + v0.z * v0.z + v0.w * v0.w +
               v1.x * v1.x + v1.y * v1.y + v1.z * v1.z + v1.w * v1.w;
    for (int off = 1; off < 64; off <<= 1) {
        sum += __shfl_xor(sum, off);
        sq  += __shfl_xor(sq, off);
    }
    const float mean = sum * (1.f / 512.f);
    const float var = sq * (1.f / 512.f) - mean * mean;
    const float rstd = rsqrtf(var + 1e-5f);
    float4 g0 = *reinterpret_cast<const float4*>(&gamma[lane * 8]);
    float4 g1 = *reinterpret_cast<const float4*>(&gamma[lane * 8 + 4]);
    float4 b0 = *reinterpret_cast<const float4*>(&beta[lane * 8]);
    float4 b1 = *reinterpret_cast<const float4*>(&beta[lane * 8 + 4]);
    float4 o0, o1;
    o0.x = (v0.x - mean) * rstd * g0.x + b0.x;
    o0.y = (v0.y - mean) * rstd * g0.y + b0.y;
    o0.z = (v0.z - mean) * rstd * g0.z + b0.z;
    o0.w = (v0.w - mean) * rstd * g0.w + b0.w;
    o1.x = (v1.x - mean) * rstd * g1.x + b1.x;
    o1.y = (v1.y - mean) * rstd * g1.y + b1.y;
    o1.z = (v1.z - mean) * rstd * g1.z + b1.z;
    o1.w = (v1.w - mean) * rstd * g1.w + b1.w;
    *reinterpret_cast<float4*>(&out[(size_t)row * 512 + lane * 8]) = o0;
    *reinterpret_cast<float4*>(&out[(size_t)row * 512 + lane * 8 + 4]) = o1;
}

// ---------------------------------------------------------------------------
extern "C" void kernel_launch(void* const* d_in, const int* in_sizes, int n_in,
                              void* d_out, int out_size, void* d_ws, size_t ws_size,
                              hipStream_t stream)
{
    const float* query = (const float*)d_in[0];
    const float* key   = (const float*)d_in[1];
    const float* value = (const float*)d_in[2];
    const float* Wq    = (const float*)d_in[3];
    const float* Wk    = (const float*)d_in[4];
    const float* Wv    = (const float*)d_in[5];
    const float* Wo    = (const float*)d_in[6];
    const float* bo    = (const float*)d_in[7];
    const float* gamma = (const float*)d_in[8];
    const float* beta  = (const float*)d_in[9];

    float* out = (float*)d_out;                       // [output | attention]
    float* attn_out = out + (size_t)B_ * S_ * D_;     // offset 2*2048*512

    char* ws = (char*)d_ws;
    __bf16* Qb  = (__bf16*)(ws);                      // 4 MB, [B,S,D] bf16, pre-scaled
    __bf16* Kb  = (__bf16*)(ws + (4u << 20));         // 4 MB, [B,S,D]
    __bf16* Vt  = (__bf16*)(ws + (8u << 20));         // 4 MB, [B,H,DH,S]
    __bf16* Ctx = (__bf16*)(ws + (12u << 20));        // 4 MB, [B,S,D]
    float*  Y   = (float*)(ws + (16u << 20));         // 8 MB fp32
    float*  Linv= (float*)(ws + (24u << 20));         // 128 KB, [B*H*S]
    __bf16* Pws = (__bf16*)(ws + (32u << 20));        // 134 MB, [B*H, S, S] bf16 unnormalized

    proj_qkv<<<dim3(64, 8, 3), 256, 0, stream>>>(query, key, value, Wq, Wk, Wv, Qb, Kb, Vt);
    attn_kernel<<<dim3(32, 16), 256, 0, stream>>>(Qb, Kb, Vt, Ctx, Pws, Linv);
    rescale_kernel<<<B_ * H_ * S_, 256, 0, stream>>>(Pws, Linv, attn_out);
    oproj<<<dim3(64, 8), 256, 0, stream>>>(Ctx, Wo, bo, query, Y);
    ln_kernel<<<1024, 256, 0, stream>>>(Y, gamma, beta, out);
}

// Round 4
// 474.714 us; speedup vs baseline: 1.0276x; 1.0276x over previous
//
#include <hip/hip_runtime.h>

#define B_ 2
#define S_ 2048
#define D_ 512
#define H_ 8
#define DH_ 64

typedef __bf16 bf16_8 __attribute__((ext_vector_type(8)));
typedef float f32x4 __attribute__((ext_vector_type(4)));
typedef unsigned int u32x4 __attribute__((ext_vector_type(4)));

union BfPack4 { ushort4 u; __bf16 h[4]; };

// ---------------------------------------------------------------------------
// Kernel 1: QKV projection.  y = x @ W^T  (torch Linear), bf16 outputs.
// z=0: Q (scaled by 1/8), z=1: K, z=2: V stored transposed [B,H,DH,S].
// ---------------------------------------------------------------------------
__global__ __launch_bounds__(256) void proj_qkv(
    const float* __restrict__ Xq, const float* __restrict__ Xk, const float* __restrict__ Xv,
    const float* __restrict__ Wq, const float* __restrict__ Wk, const float* __restrict__ Wv,
    __bf16* __restrict__ Qb, __bf16* __restrict__ Kb, __bf16* __restrict__ Vt)
{
    const int z = blockIdx.z;
    const float* X = (z == 0) ? Xq : (z == 1) ? Xk : Xv;
    const float* W = (z == 0) ? Wq : (z == 1) ? Wk : Wv;
    const int m0 = blockIdx.x * 64;   // 0..4095
    const int n0 = blockIdx.y * 64;   // 0..511

    __shared__ __bf16 Xs[64][72];
    __shared__ __bf16 Ws[64][72];

    const int tid = threadIdx.x;
    const int w = tid >> 6, lane = tid & 63;
    const int quad = lane >> 4, mc = lane & 15;

    int rr[4], cc[4];
    for (int i = 0; i < 4; ++i) { int e = tid + i * 256; rr[i] = e >> 4; cc[i] = (e & 15) * 4; }

    f32x4 acc[4] = {};
    float4 xr[4], wv[4];
    for (int i = 0; i < 4; ++i) {
        xr[i] = *reinterpret_cast<const float4*>(&X[(size_t)(m0 + rr[i]) * 512 + cc[i]]);
        wv[i] = *reinterpret_cast<const float4*>(&W[(size_t)(n0 + rr[i]) * 512 + cc[i]]);
    }

    for (int kc = 0; kc < 512; kc += 64) {
        if (kc) __syncthreads();
        for (int i = 0; i < 4; ++i) {
            BfPack4 px, pw;
            px.h[0] = (__bf16)xr[i].x; px.h[1] = (__bf16)xr[i].y;
            px.h[2] = (__bf16)xr[i].z; px.h[3] = (__bf16)xr[i].w;
            *reinterpret_cast<ushort4*>(&Xs[rr[i]][cc[i]]) = px.u;
            pw.h[0] = (__bf16)wv[i].x; pw.h[1] = (__bf16)wv[i].y;
            pw.h[2] = (__bf16)wv[i].z; pw.h[3] = (__bf16)wv[i].w;
            *reinterpret_cast<ushort4*>(&Ws[rr[i]][cc[i]]) = pw.u;
        }
        __syncthreads();
        if (kc < 448) {
            for (int i = 0; i < 4; ++i) {
                xr[i] = *reinterpret_cast<const float4*>(&X[(size_t)(m0 + rr[i]) * 512 + kc + 64 + cc[i]]);
                wv[i] = *reinterpret_cast<const float4*>(&W[(size_t)(n0 + rr[i]) * 512 + kc + 64 + cc[i]]);
            }
        }
        for (int ks = 0; ks < 64; ks += 32) {
            bf16_8 a = *reinterpret_cast<const bf16_8*>(&Xs[w * 16 + mc][ks + quad * 8]);
            for (int tt = 0; tt < 4; ++tt) {
                bf16_8 bb = *reinterpret_cast<const bf16_8*>(&Ws[tt * 16 + mc][ks + quad * 8]);
                acc[tt] = __builtin_amdgcn_mfma_f32_16x16x32_bf16(a, bb, acc[tt], 0, 0, 0);
            }
        }
    }
    __syncthreads();
    const float scale = (z == 0) ? 0.125f : 1.0f;   // DH^-0.5 folded into Q
    if (z < 2) {
        for (int tt = 0; tt < 4; ++tt)
            for (int r = 0; r < 4; ++r)
                Xs[w * 16 + quad * 4 + r][tt * 16 + mc] = (__bf16)(acc[tt][r] * scale);
    } else {
        for (int tt = 0; tt < 4; ++tt)
            for (int r = 0; r < 4; ++r)
                Xs[tt * 16 + mc][w * 16 + quad * 4 + r] = (__bf16)acc[tt][r];  // transposed tile [dh][s]
    }
    __syncthreads();
    if (z < 2) {
        __bf16* out = (z == 0) ? Qb : Kb;
        for (int i = 0; i < 2; ++i) {
            int e = tid + i * 256;
            int r = e >> 3, c8 = (e & 7) * 8;
            *reinterpret_cast<uint4*>(&out[(size_t)(m0 + r) * 512 + n0 + c8]) =
                *reinterpret_cast<const uint4*>(&Xs[r][c8]);
        }
    } else {
        int b = m0 >> 11, s0 = m0 & 2047, h = n0 >> 6;
        for (int i = 0; i < 2; ++i) {
            int e = tid + i * 256;
            int r = e >> 3, c8 = (e & 7) * 8;   // r = dh, c8 = s offset
            *reinterpret_cast<uint4*>(&Vt[(((size_t)(b * H_ + h)) * DH_ + r) * S_ + s0 + c8]) =
                *reinterpret_cast<const uint4*>(&Xs[r][c8]);
        }
    }
}

// ---------------------------------------------------------------------------
// Kernel 2: single-pass barrier-free attention.
// WG = 4 waves, 16 q-rows. Wave kg owns k-range [kg*512, kg*512+512).
// K/V fragments load DIRECTLY from global (per-(b,h) K+V = 512 KB, L2-hit;
// no LDS staging, no main-loop barriers). p=exp(s) stashed in a wave-private
// LDS strip; l accumulates lane-locally. End: combine l across waves (one
// barrier), write normalized attention fp32 (NT) once, combine PV partials
// via LDS overlay, write normalized Ctx bf16.
// LDS 67.8 KB -> 2 WG/CU (8 waves/CU).
// ---------------------------------------------------------------------------
__global__ __launch_bounds__(256) void attn_kernel(
    const __bf16* __restrict__ Qb, const __bf16* __restrict__ Kb, const __bf16* __restrict__ Vt,
    __bf16* __restrict__ Ctx, float* __restrict__ attn_out)
{
    const int qt = blockIdx.x;        // 0..127 (16-row q tiles)
    const int bh = blockIdx.y;        // 0..15
    const int b = bh >> 3, h = bh & 7;
    const int q0 = qt * 16;

    // Ps: [4 waves][16 rows][528 cols] bf16 = 67584 B; Osc overlays after use.
    __shared__ __align__(16) char smem[4 * 16 * 528 * 2];
    __shared__ float Lsh[4][16];

    const int tid = threadIdx.x;
    const int kg = tid >> 6, lane = tid & 63;
    const int quad = lane >> 4, mc = lane & 15;

    __bf16* PsW = reinterpret_cast<__bf16*>(smem) + (size_t)kg * 16 * 528;

    // Q fragments straight from global (row = mc, dh split in two halves)
    const __bf16* qrow = &Qb[((size_t)b * S_ + q0 + mc) * D_ + h * DH_];
    const bf16_8 aq0 = *reinterpret_cast<const bf16_8*>(&qrow[quad * 8]);
    const bf16_8 aq1 = *reinterpret_cast<const bf16_8*>(&qrow[32 + quad * 8]);

    const __bf16* kbase = Kb + ((size_t)b * S_ + kg * 512) * D_ + h * DH_;
    const __bf16* vbase = Vt + (size_t)bh * DH_ * S_ + kg * 512;

    float l[4] = {0.f, 0.f, 0.f, 0.f};
    f32x4 o[4] = {};

    for (int c = 0; c < 8; ++c) {          // 8 chunks of 64 k within this wave's range
        const __bf16* kc_ = kbase + (size_t)c * 64 * D_;
        // ---- QK^T: 8 global B-frag loads (L2), then 8 MFMAs ----
        bf16_8 kb[8];
        for (int tt = 0; tt < 4; ++tt)
            kb[tt] = *reinterpret_cast<const bf16_8*>(&kc_[(size_t)(tt * 16 + mc) * D_ + quad * 8]);
        for (int tt = 0; tt < 4; ++tt)
            kb[4 + tt] = *reinterpret_cast<const bf16_8*>(&kc_[(size_t)(tt * 16 + mc) * D_ + 32 + quad * 8]);
        f32x4 s[4] = {};
        for (int tt = 0; tt < 4; ++tt)
            s[tt] = __builtin_amdgcn_mfma_f32_16x16x32_bf16(aq0, kb[tt], s[tt], 0, 0, 0);
        for (int tt = 0; tt < 4; ++tt)
            s[tt] = __builtin_amdgcn_mfma_f32_16x16x32_bf16(aq1, kb[4 + tt], s[tt], 0, 0, 0);
        // ---- p = exp(s), lane-local l, stash to wave-private LDS ----
        for (int tt = 0; tt < 4; ++tt)
            for (int j = 0; j < 4; ++j) {
                float p = __expf(s[tt][j]);
                l[j] += p;
                PsW[(size_t)(quad * 4 + j) * 528 + c * 64 + tt * 16 + mc] = (__bf16)p;
            }
        // ---- PV: A from Ps, B from global Vt (L2) ----
        bf16_8 vb[8];
        for (int ks2 = 0; ks2 < 2; ++ks2)
            for (int tt = 0; tt < 4; ++tt)
                vb[ks2 * 4 + tt] = *reinterpret_cast<const bf16_8*>(
                    &vbase[(size_t)(tt * 16 + mc) * S_ + c * 64 + ks2 * 32 + quad * 8]);
        for (int ks2 = 0; ks2 < 2; ++ks2) {
            bf16_8 ap = *reinterpret_cast<const bf16_8*>(&PsW[(size_t)mc * 528 + c * 64 + ks2 * 32 + quad * 8]);
            for (int tt = 0; tt < 4; ++tt)
                o[tt] = __builtin_amdgcn_mfma_f32_16x16x32_bf16(ap, vb[ks2 * 4 + tt], o[tt], 0, 0, 0);
        }
    }

    // ---- combine l across mc lanes, then across the 4 waves ----
    for (int j = 0; j < 4; ++j)
        for (int off = 1; off < 16; off <<= 1) l[j] += __shfl_xor(l[j], off);
    if (mc == 0)
        for (int j = 0; j < 4; ++j) Lsh[kg][quad * 4 + j] = l[j];
    __syncthreads();

    // ---- normalized attention write: wave kg covers cols [kg*512, +512) ----
    for (int row = 0; row < 16; ++row) {
        const float li = 1.f / (Lsh[0][row] + Lsh[1][row] + Lsh[2][row] + Lsh[3][row]);
        u32x4 pv = *reinterpret_cast<const u32x4*>(&PsW[(size_t)row * 528 + lane * 8]);
        const __bf16* pp = reinterpret_cast<const __bf16*>(&pv);
        f32x4 lo, hi;
        for (int j = 0; j < 4; ++j) {
            lo[j] = (float)pp[j] * li;
            hi[j] = (float)pp[j + 4] * li;
        }
        float* dst = &attn_out[((size_t)bh * S_ + q0 + row) * S_ + kg * 512 + lane * 8];
        __builtin_nontemporal_store(lo, reinterpret_cast<f32x4*>(dst));
        __builtin_nontemporal_store(hi, reinterpret_cast<f32x4*>(dst + 4));
    }
    __syncthreads();   // all Ps reads done -> smem reusable as Osc

    // ---- combine PV partials via overlay, write Ctx normalized bf16 ----
    float* Osc = reinterpret_cast<float*>(smem);   // [4][16][68] f32 = 17.4 KB
    for (int tt = 0; tt < 4; ++tt)
        for (int j = 0; j < 4; ++j)
            Osc[(size_t)kg * 16 * 68 + (quad * 4 + j) * 68 + tt * 16 + mc] = o[tt][j];
    __syncthreads();
    {
        const int row = tid >> 4;          // 0..15
        const int dhg = (tid & 15) * 4;    // 0..60
        const float li = 1.f / (Lsh[0][row] + Lsh[1][row] + Lsh[2][row] + Lsh[3][row]);
        BfPack4 pk;
        for (int kk = 0; kk < 4; ++kk) {
            float v = Osc[(size_t)0 * 16 * 68 + row * 68 + dhg + kk]
                    + Osc[(size_t)1 * 16 * 68 + row * 68 + dhg + kk]
                    + Osc[(size_t)2 * 16 * 68 + row * 68 + dhg + kk]
                    + Osc[(size_t)3 * 16 * 68 + row * 68 + dhg + kk];
            pk.h[kk] = (__bf16)(v * li);
        }
        *reinterpret_cast<ushort4*>(&Ctx[((size_t)b * S_ + q0 + row) * D_ + h * DH_ + dhg]) = pk.u;
    }
}

// ---------------------------------------------------------------------------
// Kernel 3a: output projection + bias + residual -> fp32 ws
// ---------------------------------------------------------------------------
__global__ __launch_bounds__(256) void oproj(
    const __bf16* __restrict__ Ctx, const float* __restrict__ Wo,
    const float* __restrict__ bo, const float* __restrict__ resid,
    float* __restrict__ Y)
{
    const int m0 = blockIdx.x * 64;
    const int n0 = blockIdx.y * 64;

    __shared__ __bf16 As[64][72];
    __shared__ __bf16 Bs[64][72];

    const int tid = threadIdx.x;
    const int w = tid >> 6, lane = tid & 63;
    const int quad = lane >> 4, mc = lane & 15;

    int ar[2], ac[2], wr2[4], wc2[4];
    for (int i = 0; i < 2; ++i) { int e = tid + i * 256; ar[i] = e >> 3; ac[i] = (e & 7) * 8; }
    for (int i = 0; i < 4; ++i) { int e = tid + i * 256; wr2[i] = e >> 4; wc2[i] = (e & 15) * 4; }

    uint4 areg[2];
    float4 wreg[4];
    for (int i = 0; i < 2; ++i)
        areg[i] = *reinterpret_cast<const uint4*>(&Ctx[(size_t)(m0 + ar[i]) * 512 + ac[i]]);
    for (int i = 0; i < 4; ++i)
        wreg[i] = *reinterpret_cast<const float4*>(&Wo[(size_t)(n0 + wr2[i]) * 512 + wc2[i]]);

    f32x4 acc[4] = {};
    for (int kc = 0; kc < 512; kc += 64) {
        if (kc) __syncthreads();
        for (int i = 0; i < 2; ++i)
            *reinterpret_cast<uint4*>(&As[ar[i]][ac[i]]) = areg[i];
        for (int i = 0; i < 4; ++i) {
            BfPack4 pw;
            pw.h[0] = (__bf16)wreg[i].x; pw.h[1] = (__bf16)wreg[i].y;
            pw.h[2] = (__bf16)wreg[i].z; pw.h[3] = (__bf16)wreg[i].w;
            *reinterpret_cast<ushort4*>(&Bs[wr2[i]][wc2[i]]) = pw.u;
        }
        __syncthreads();
        if (kc < 448) {
            for (int i = 0; i < 2; ++i)
                areg[i] = *reinterpret_cast<const uint4*>(&Ctx[(size_t)(m0 + ar[i]) * 512 + kc + 64 + ac[i]]);
            for (int i = 0; i < 4; ++i)
                wreg[i] = *reinterpret_cast<const float4*>(&Wo[(size_t)(n0 + wr2[i]) * 512 + kc + 64 + wc2[i]]);
        }
        for (int ks = 0; ks < 64; ks += 32) {
            bf16_8 a = *reinterpret_cast<const bf16_8*>(&As[w * 16 + mc][ks + quad * 8]);
            for (int tt = 0; tt < 4; ++tt) {
                bf16_8 bb = *reinterpret_cast<const bf16_8*>(&Bs[tt * 16 + mc][ks + quad * 8]);
                acc[tt] = __builtin_amdgcn_mfma_f32_16x16x32_bf16(a, bb, acc[tt], 0, 0, 0);
            }
        }
    }
    for (int tt = 0; tt < 4; ++tt) {
        int col = n0 + tt * 16 + mc;
        float bias = bo[col];
        for (int r = 0; r < 4; ++r) {
            int row = m0 + w * 16 + quad * 4 + r;
            Y[(size_t)row * 512 + col] = acc[tt][r] + bias + resid[(size_t)row * 512 + col];
        }
    }
}

// ---------------------------------------------------------------------------
// Kernel 3b: LayerNorm over last dim (512). One wave per row.
// ---------------------------------------------------------------------------
__global__ __launch_bounds__(256) void ln_kernel(
    const float* __restrict__ Y, const float* __restrict__ gamma,
    const float* __restrict__ beta, float* __restrict__ out)
{
    const int row = blockIdx.x * 4 + (threadIdx.x >> 6);
    const int lane = threadIdx.x & 63;
    const float* y = &Y[(size_t)row * 512];
    float4 v0 = *reinterpret_cast<const float4*>(&y[lane * 8]);
    float4 v1 = *reinterpret_cast<const float4*>(&y[lane * 8 + 4]);
    float sum = v0.x + v0.y + v0.z + v0.w + v1.x + v1.y + v1.z + v1.w;
    float sq = v0.x * v0.x + v0.y * v0.y + v0.z * v0.z + v0.w * v0.w +
               v1.x * v1.x + v1.y * v1.y + v1.z * v1.z + v1.w * v1.w;
    for (int off = 1; off < 64; off <<= 1) {
        sum += __shfl_xor(sum, off);
        sq  += __shfl_xor(sq, off);
    }
    const float mean = sum * (1.f / 512.f);
    const float var = sq * (1.f / 512.f) - mean * mean;
    const float rstd = rsqrtf(var + 1e-5f);
    float4 g0 = *reinterpret_cast<const float4*>(&gamma[lane * 8]);
    float4 g1 = *reinterpret_cast<const float4*>(&gamma[lane * 8 + 4]);
    float4 b0 = *reinterpret_cast<const float4*>(&beta[lane * 8]);
    float4 b1 = *reinterpret_cast<const float4*>(&beta[lane * 8 + 4]);
    float4 o0, o1;
    o0.x = (v0.x - mean) * rstd * g0.x + b0.x;
    o0.y = (v0.y - mean) * rstd * g0.y + b0.y;
    o0.z = (v0.z - mean) * rstd * g0.z + b0.z;
    o0.w = (v0.w - mean) * rstd * g0.w + b0.w;
    o1.x = (v1.x - mean) * rstd * g1.x + b1.x;
    o1.y = (v1.y - mean) * rstd * g1.y + b1.y;
    o1.z = (v1.z - mean) * rstd * g1.z + b1.z;
    o1.w = (v1.w - mean) * rstd * g1.w + b1.w;
    *reinterpret_cast<float4*>(&out[(size_t)row * 512 + lane * 8]) = o0;
    *reinterpret_cast<float4*>(&out[(size_t)row * 512 + lane * 8 + 4]) = o1;
}

// ---------------------------------------------------------------------------
extern "C" void kernel_launch(void* const* d_in, const int* in_sizes, int n_in,
                              void* d_out, int out_size, void* d_ws, size_t ws_size,
                              hipStream_t stream)
{
    const float* query = (const float*)d_in[0];
    const float* key   = (const float*)d_in[1];
    const float* value = (const float*)d_in[2];
    const float* Wq    = (const float*)d_in[3];
    const float* Wk    = (const float*)d_in[4];
    const float* Wv    = (const float*)d_in[5];
    const float* Wo    = (const float*)d_in[6];
    const float* bo    = (const float*)d_in[7];
    const float* gamma = (const float*)d_in[8];
    const float* beta  = (const float*)d_in[9];

    float* out = (float*)d_out;                       // [output | attention]
    float* attn_out = out + (size_t)B_ * S_ * D_;     // offset 2*2048*512

    char* ws = (char*)d_ws;
    __bf16* Qb  = (__bf16*)(ws);                      // 4 MB, [B,S,D] bf16, pre-scaled
    __bf16* Kb  = (__bf16*)(ws + (4u << 20));         // 4 MB, [B,S,D]
    __bf16* Vt  = (__bf16*)(ws + (8u << 20));         // 4 MB, [B,H,DH,S]
    __bf16* Ctx = (__bf16*)(ws + (12u << 20));        // 4 MB, [B,S,D]
    float*  Y   = (float*)(ws + (16u << 20));         // 8 MB fp32

    proj_qkv<<<dim3(64, 8, 3), 256, 0, stream>>>(query, key, value, Wq, Wk, Wv, Qb, Kb, Vt);
    attn_kernel<<<dim3(128, 16), 256, 0, stream>>>(Qb, Kb, Vt, Ctx, attn_out);
    oproj<<<dim3(64, 8), 256, 0, stream>>>(Ctx, Wo, bo, query, Y);
    ln_kernel<<<1024, 256, 0, stream>>>(Y, gamma, beta, out);
}

// Round 7
// 449.675 us; speedup vs baseline: 1.0848x; 1.0557x over previous
//
#include <hip/hip_runtime.h>

#define B_ 2
#define S_ 2048
#define D_ 512
#define H_ 8
#define DH_ 64

typedef __bf16 bf16_8 __attribute__((ext_vector_type(8)));
typedef float f32x4 __attribute__((ext_vector_type(4)));
typedef unsigned int u32x4 __attribute__((ext_vector_type(4)));

union BfPack4 { ushort4 u; __bf16 h[4]; };

// ---------------------------------------------------------------------------
// Kernel 1: QKV projection.  y = x @ W^T  (torch Linear), bf16 outputs.
// z=0: Q (scaled by 1/8), z=1: K, z=2: V stored transposed [B,H,DH,S].
// ---------------------------------------------------------------------------
__global__ __launch_bounds__(256) void proj_qkv(
    const float* __restrict__ Xq, const float* __restrict__ Xk, const float* __restrict__ Xv,
    const float* __restrict__ Wq, const float* __restrict__ Wk, const float* __restrict__ Wv,
    __bf16* __restrict__ Qb, __bf16* __restrict__ Kb, __bf16* __restrict__ Vt)
{
    const int z = blockIdx.z;
    const float* X = (z == 0) ? Xq : (z == 1) ? Xk : Xv;
    const float* W = (z == 0) ? Wq : (z == 1) ? Wk : Wv;
    const int m0 = blockIdx.x * 64;   // 0..4095
    const int n0 = blockIdx.y * 64;   // 0..511

    __shared__ __bf16 Xs[64][72];
    __shared__ __bf16 Ws[64][72];

    const int tid = threadIdx.x;
    const int w = tid >> 6, lane = tid & 63;
    const int quad = lane >> 4, mc = lane & 15;

    int rr[4], cc[4];
    for (int i = 0; i < 4; ++i) { int e = tid + i * 256; rr[i] = e >> 4; cc[i] = (e & 15) * 4; }

    f32x4 acc[4] = {};
    float4 xr[4], wv[4];
    for (int i = 0; i < 4; ++i) {
        xr[i] = *reinterpret_cast<const float4*>(&X[(size_t)(m0 + rr[i]) * 512 + cc[i]]);
        wv[i] = *reinterpret_cast<const float4*>(&W[(size_t)(n0 + rr[i]) * 512 + cc[i]]);
    }

    for (int kc = 0; kc < 512; kc += 64) {
        if (kc) __syncthreads();
        for (int i = 0; i < 4; ++i) {
            BfPack4 px, pw;
            px.h[0] = (__bf16)xr[i].x; px.h[1] = (__bf16)xr[i].y;
            px.h[2] = (__bf16)xr[i].z; px.h[3] = (__bf16)xr[i].w;
            *reinterpret_cast<ushort4*>(&Xs[rr[i]][cc[i]]) = px.u;
            pw.h[0] = (__bf16)wv[i].x; pw.h[1] = (__bf16)wv[i].y;
            pw.h[2] = (__bf16)wv[i].z; pw.h[3] = (__bf16)wv[i].w;
            *reinterpret_cast<ushort4*>(&Ws[rr[i]][cc[i]]) = pw.u;
        }
        __syncthreads();
        if (kc < 448) {
            for (int i = 0; i < 4; ++i) {
                xr[i] = *reinterpret_cast<const float4*>(&X[(size_t)(m0 + rr[i]) * 512 + kc + 64 + cc[i]]);
                wv[i] = *reinterpret_cast<const float4*>(&W[(size_t)(n0 + rr[i]) * 512 + kc + 64 + cc[i]]);
            }
        }
        for (int ks = 0; ks < 64; ks += 32) {
            bf16_8 a = *reinterpret_cast<const bf16_8*>(&Xs[w * 16 + mc][ks + quad * 8]);
            for (int tt = 0; tt < 4; ++tt) {
                bf16_8 bb = *reinterpret_cast<const bf16_8*>(&Ws[tt * 16 + mc][ks + quad * 8]);
                acc[tt] = __builtin_amdgcn_mfma_f32_16x16x32_bf16(a, bb, acc[tt], 0, 0, 0);
            }
        }
    }
    __syncthreads();
    const float scale = (z == 0) ? 0.125f : 1.0f;   // DH^-0.5 folded into Q
    if (z < 2) {
        for (int tt = 0; tt < 4; ++tt)
            for (int r = 0; r < 4; ++r)
                Xs[w * 16 + quad * 4 + r][tt * 16 + mc] = (__bf16)(acc[tt][r] * scale);
    } else {
        for (int tt = 0; tt < 4; ++tt)
            for (int r = 0; r < 4; ++r)
                Xs[tt * 16 + mc][w * 16 + quad * 4 + r] = (__bf16)acc[tt][r];  // transposed tile [dh][s]
    }
    __syncthreads();
    if (z < 2) {
        __bf16* out = (z == 0) ? Qb : Kb;
        for (int i = 0; i < 2; ++i) {
            int e = tid + i * 256;
            int r = e >> 3, c8 = (e & 7) * 8;
            *reinterpret_cast<uint4*>(&out[(size_t)(m0 + r) * 512 + n0 + c8]) =
                *reinterpret_cast<const uint4*>(&Xs[r][c8]);
        }
    } else {
        int b = m0 >> 11, s0 = m0 & 2047, h = n0 >> 6;
        for (int i = 0; i < 2; ++i) {
            int e = tid + i * 256;
            int r = e >> 3, c8 = (e & 7) * 8;   // r = dh, c8 = s offset
            *reinterpret_cast<uint4*>(&Vt[(((size_t)(b * H_ + h)) * DH_ + r) * S_ + s0 + c8]) =
                *reinterpret_cast<const uint4*>(&Xs[r][c8]);
        }
    }
}

// ---------------------------------------------------------------------------
// Kernel 2: single-pass attention, 8 waves/WG (512 thr) for latency hiding.
// 16 q-rows per WG. Wave kg owns k-cols [kg*256, +256), 4 chunks of 64, with
// per-chunk K/V frag loads (kb[8]/vb[8] reused, next-chunk K issued after QK,
// next-chunk V after PV -> ~120 VGPR under __launch_bounds__(512,4) cap 128).
// K/V straight from L2 (512 KB per (b,h)); main phase has no barriers.
// p=exp(s) stashed in wave-private LDS strip [16][264]; l lane-local.
// End: combine l across 8 waves, write normalized attention fp32 (NT, f32x4
// per lane), combine PV partials via LDS overlay, write Ctx bf16.
// LDS ~66 KB -> 2 WG/CU = 16 waves/CU (2x the round-4 variant's 8).
// ---------------------------------------------------------------------------
__global__ __launch_bounds__(512, 4) void attn_kernel(
    const __bf16* __restrict__ Qb, const __bf16* __restrict__ Kb, const __bf16* __restrict__ Vt,
    __bf16* __restrict__ Ctx, float* __restrict__ attn_out)
{
    const int qt = blockIdx.x;        // 0..127 (16-row q tiles)
    const int bh = blockIdx.y;        // 0..15
    const int b = bh >> 3, h = bh & 7;
    const int q0 = qt * 16;

    // PsW: [8 waves][16 rows][264 cols] bf16 = 67584 B; Osc overlays after.
    __shared__ __align__(16) char smem[8 * 16 * 264 * 2];
    __shared__ float Lsh[8][16];
    __shared__ float linv_s[16];

    const int tid = threadIdx.x;
    const int kg = tid >> 6, lane = tid & 63;
    const int quad = lane >> 4, mc = lane & 15;

    __bf16* PsW = reinterpret_cast<__bf16*>(smem) + kg * 16 * 264;

    // Q fragments straight from global (row = mc, dh split in two halves)
    const __bf16* qrow = &Qb[((size_t)b * S_ + q0 + mc) * D_ + h * DH_];
    const bf16_8 aq0 = *reinterpret_cast<const bf16_8*>(&qrow[quad * 8]);
    const bf16_8 aq1 = *reinterpret_cast<const bf16_8*>(&qrow[32 + quad * 8]);

    const __bf16* kbase = Kb + ((size_t)b * S_ + kg * 256) * D_ + h * DH_;
    const __bf16* vbase = Vt + (size_t)bh * DH_ * S_ + kg * 256;

    float l[4] = {0.f, 0.f, 0.f, 0.f};
    f32x4 o[4] = {};
    bf16_8 kb[8], vb[8];

    auto loadK = [&](int c) {
        for (int tt = 0; tt < 4; ++tt) {
            const __bf16* kr = &kbase[(size_t)(c * 64 + tt * 16 + mc) * D_];
            kb[tt]     = *reinterpret_cast<const bf16_8*>(&kr[quad * 8]);
            kb[4 + tt] = *reinterpret_cast<const bf16_8*>(&kr[32 + quad * 8]);
        }
    };
    auto loadV = [&](int c) {
        for (int ks2 = 0; ks2 < 2; ++ks2)
            for (int tt = 0; tt < 4; ++tt)
                vb[ks2 * 4 + tt] = *reinterpret_cast<const bf16_8*>(
                    &vbase[(size_t)(tt * 16 + mc) * S_ + c * 64 + ks2 * 32 + quad * 8]);
    };

    loadK(0);
    loadV(0);
#pragma unroll
    for (int c = 0; c < 4; ++c) {
        // ---- QK chunk c ----
        f32x4 s[4] = {};
        for (int tt = 0; tt < 4; ++tt)
            s[tt] = __builtin_amdgcn_mfma_f32_16x16x32_bf16(aq0, kb[tt], s[tt], 0, 0, 0);
        for (int tt = 0; tt < 4; ++tt)
            s[tt] = __builtin_amdgcn_mfma_f32_16x16x32_bf16(aq1, kb[4 + tt], s[tt], 0, 0, 0);
        // ---- p = exp(s), lane-local l, stash ----
        for (int tt = 0; tt < 4; ++tt)
            for (int j = 0; j < 4; ++j) {
                float p = __expf(s[tt][j]);
                l[j] += p;
                PsW[(quad * 4 + j) * 264 + c * 64 + tt * 16 + mc] = (__bf16)p;
            }
        // ---- prefetch next K (kb dead after QK) ----
        if (c < 3) loadK(c + 1);
        // ---- PV chunk c ----
        for (int ks2 = 0; ks2 < 2; ++ks2) {
            bf16_8 ap = *reinterpret_cast<const bf16_8*>(
                &PsW[mc * 264 + c * 64 + ks2 * 32 + quad * 8]);
            for (int tt = 0; tt < 4; ++tt)
                o[tt] = __builtin_amdgcn_mfma_f32_16x16x32_bf16(ap, vb[ks2 * 4 + tt], o[tt], 0, 0, 0);
        }
        // ---- prefetch next V (vb dead after PV) ----
        if (c < 3) loadV(c + 1);
    }

    // ---- combine l: across mc lanes, then across the 8 waves ----
    for (int j = 0; j < 4; ++j)
        for (int off = 1; off < 16; off <<= 1) l[j] += __shfl_xor(l[j], off);
    if (mc == 0)
        for (int j = 0; j < 4; ++j) Lsh[kg][quad * 4 + j] = l[j];
    __syncthreads();
    if (tid < 16) {
        float t = 0.f;
        for (int g = 0; g < 8; ++g) t += Lsh[g][tid];
        linv_s[tid] = 1.f / t;
    }
    __syncthreads();

    // ---- normalized attention write: wave kg covers cols [kg*256, +256) ----
    for (int r = 0; r < 16; ++r) {
        const float li = linv_s[r];
        BfPack4 pu;
        pu.u = *reinterpret_cast<const ushort4*>(&PsW[r * 264 + lane * 4]);
        f32x4 ov;
        for (int j = 0; j < 4; ++j) ov[j] = (float)pu.h[j] * li;
        __builtin_nontemporal_store(ov, reinterpret_cast<f32x4*>(
            &attn_out[((size_t)bh * S_ + q0 + r) * S_ + kg * 256 + lane * 4]));
    }
    __syncthreads();   // all Ps reads done -> smem reusable as Osc

    // ---- combine PV partials via overlay, write Ctx normalized bf16 ----
    float* Osc = reinterpret_cast<float*>(smem);   // [8][16][68] f32 = 34816 B
    for (int tt = 0; tt < 4; ++tt)
        for (int j = 0; j < 4; ++j)
            Osc[(kg * 16 + quad * 4 + j) * 68 + tt * 16 + mc] = o[tt][j];
    __syncthreads();
    if (tid < 256) {
        const int row = tid >> 4;          // 0..15
        const int dhg = (tid & 15) * 4;    // 0..60
        const float li = linv_s[row];
        BfPack4 pk;
        for (int kk = 0; kk < 4; ++kk) {
            float v = 0.f;
            for (int g = 0; g < 8; ++g)
                v += Osc[(g * 16 + row) * 68 + dhg + kk];
            pk.h[kk] = (__bf16)(v * li);
        }
        *reinterpret_cast<ushort4*>(&Ctx[((size_t)b * S_ + q0 + row) * D_ + h * DH_ + dhg]) = pk.u;
    }
}

// ---------------------------------------------------------------------------
// Kernel 3a: output projection + bias + residual -> fp32 ws
// ---------------------------------------------------------------------------
__global__ __launch_bounds__(256) void oproj(
    const __bf16* __restrict__ Ctx, const float* __restrict__ Wo,
    const float* __restrict__ bo, const float* __restrict__ resid,
    float* __restrict__ Y)
{
    const int m0 = blockIdx.x * 64;
    const int n0 = blockIdx.y * 64;

    __shared__ __bf16 As[64][72];
    __shared__ __bf16 Bs[64][72];

    const int tid = threadIdx.x;
    const int w = tid >> 6, lane = tid & 63;
    const int quad = lane >> 4, mc = lane & 15;

    int ar[2], ac[2], wr2[4], wc2[4];
    for (int i = 0; i < 2; ++i) { int e = tid + i * 256; ar[i] = e >> 3; ac[i] = (e & 7) * 8; }
    for (int i = 0; i < 4; ++i) { int e = tid + i * 256; wr2[i] = e >> 4; wc2[i] = (e & 15) * 4; }

    uint4 areg[2];
    float4 wreg[4];
    for (int i = 0; i < 2; ++i)
        areg[i] = *reinterpret_cast<const uint4*>(&Ctx[(size_t)(m0 + ar[i]) * 512 + ac[i]]);
    for (int i = 0; i < 4; ++i)
        wreg[i] = *reinterpret_cast<const float4*>(&Wo[(size_t)(n0 + wr2[i]) * 512 + wc2[i]]);

    f32x4 acc[4] = {};
    for (int kc = 0; kc < 512; kc += 64) {
        if (kc) __syncthreads();
        for (int i = 0; i < 2; ++i)
            *reinterpret_cast<uint4*>(&As[ar[i]][ac[i]]) = areg[i];
        for (int i = 0; i < 4; ++i) {
            BfPack4 pw;
            pw.h[0] = (__bf16)wreg[i].x; pw.h[1] = (__bf16)wreg[i].y;
            pw.h[2] = (__bf16)wreg[i].z; pw.h[3] = (__bf16)wreg[i].w;
            *reinterpret_cast<ushort4*>(&Bs[wr2[i]][wc2[i]]) = pw.u;
        }
        __syncthreads();
        if (kc < 448) {
            for (int i = 0; i < 2; ++i)
                areg[i] = *reinterpret_cast<const uint4*>(&Ctx[(size_t)(m0 + ar[i]) * 512 + kc + 64 + ac[i]]);
            for (int i = 0; i < 4; ++i)
                wreg[i] = *reinterpret_cast<const float4*>(&Wo[(size_t)(n0 + wr2[i]) * 512 + kc + 64 + wc2[i]]);
        }
        for (int ks = 0; ks < 64; ks += 32) {
            bf16_8 a = *reinterpret_cast<const bf16_8*>(&As[w * 16 + mc][ks + quad * 8]);
            for (int tt = 0; tt < 4; ++tt) {
                bf16_8 bb = *reinterpret_cast<const bf16_8*>(&Bs[tt * 16 + mc][ks + quad * 8]);
                acc[tt] = __builtin_amdgcn_mfma_f32_16x16x32_bf16(a, bb, acc[tt], 0, 0, 0);
            }
        }
    }
    for (int tt = 0; tt < 4; ++tt) {
        int col = n0 + tt * 16 + mc;
        float bias = bo[col];
        for (int r = 0; r < 4; ++r) {
            int row = m0 + w * 16 + quad * 4 + r;
            Y[(size_t)row * 512 + col] = acc[tt][r] + bias + resid[(size_t)row * 512 + col];
        }
    }
}

// ---------------------------------------------------------------------------
// Kernel 3b: LayerNorm over last dim (512). One wave per row.
// ---------------------------------------------------------------------------
__global__ __launch_bounds__(256) void ln_kernel(
    const float* __restrict__ Y, const float* __restrict__ gamma,
    const float* __restrict__ beta, float* __restrict__ out)
{
    const int row = blockIdx.x * 4 + (threadIdx.x >> 6);
    const int lane = threadIdx.x & 63;
    const float* y = &Y[(size_t)row * 512];
    float4 v0 = *reinterpret_cast<const float4*>(&y[lane * 8]);
    float4 v1 = *reinterpret_cast<const float4*>(&y[lane * 8 + 4]);
    float sum = v0.x + v0.y + v0.z + v0.w + v1.x + v1.y + v1.z + v1.w;
    float sq = v0.x * v0.x + v0.y * v0.y + v0.z * v0.z + v0.w * v0.w +
               v1.x * v1.x + v1.y * v1.y + v1.z * v1.z + v1.w * v1.w;
    for (int off = 1; off < 64; off <<= 1) {
        sum += __shfl_xor(sum, off);
        sq  += __shfl_xor(sq, off);
    }
    const float mean = sum * (1.f / 512.f);
    const float var = sq * (1.f / 512.f) - mean * mean;
    const float rstd = rsqrtf(var + 1e-5f);
    float4 g0 = *reinterpret_cast<const float4*>(&gamma[lane * 8]);
    float4 g1 = *reinterpret_cast<const float4*>(&gamma[lane * 8 + 4]);
    float4 b0 = *reinterpret_cast<const float4*>(&beta[lane * 8]);
    float4 b1 = *reinterpret_cast<const float4*>(&beta[lane * 8 + 4]);
    float4 o0, o1;
    o0.x = (v0.x - mean) * rstd * g0.x + b0.x;
    o0.y = (v0.y - mean) * rstd * g0.y + b0.y;
    o0.z = (v0.z - mean) * rstd * g0.z + b0.z;
    o0.w = (v0.w - mean) * rstd * g0.w + b0.w;
    o1.x = (v1.x - mean) * rstd * g1.x + b1.x;
    o1.y = (v1.y - mean) * rstd * g1.y + b1.y;
    o1.z = (v1.z - mean) * rstd * g1.z + b1.z;
    o1.w = (v1.w - mean) * rstd * g1.w + b1.w;
    *reinterpret_cast<float4*>(&out[(size_t)row * 512 + lane * 8]) = o0;
    *reinterpret_cast<float4*>(&out[(size_t)row * 512 + lane * 8 + 4]) = o1;
}

// ---------------------------------------------------------------------------
extern "C" void kernel_launch(void* const* d_in, const int* in_sizes, int n_in,
                              void* d_out, int out_size, void* d_ws, size_t ws_size,
                              hipStream_t stream)
{
    const float* query = (const float*)d_in[0];
    const float* key   = (const float*)d_in[1];
    const float* value = (const float*)d_in[2];
    const float* Wq    = (const float*)d_in[3];
    const float* Wk    = (const float*)d_in[4];
    const float* Wv    = (const float*)d_in[5];
    const float* Wo    = (const float*)d_in[6];
    const float* bo    = (const float*)d_in[7];
    const float* gamma = (const float*)d_in[8];
    const float* beta  = (const float*)d_in[9];

    float* out = (float*)d_out;                       // [output | attention]
    float* attn_out = out + (size_t)B_ * S_ * D_;     // offset 2*2048*512

    char* ws = (char*)d_ws;
    __bf16* Qb  = (__bf16*)(ws);                      // 4 MB, [B,S,D] bf16, pre-scaled
    __bf16* Kb  = (__bf16*)(ws + (4u << 20));         // 4 MB, [B,S,D]
    __bf16* Vt  = (__bf16*)(ws + (8u << 20));         // 4 MB, [B,H,DH,S]
    __bf16* Ctx = (__bf16*)(ws + (12u << 20));        // 4 MB, [B,S,D]
    float*  Y   = (float*)(ws + (16u << 20));         // 8 MB fp32

    proj_qkv<<<dim3(64, 8, 3), 256, 0, stream>>>(query, key, value, Wq, Wk, Wv, Qb, Kb, Vt);
    attn_kernel<<<dim3(128, 16), 512, 0, stream>>>(Qb, Kb, Vt, Ctx, attn_out);
    oproj<<<dim3(64, 8), 256, 0, stream>>>(Ctx, Wo, bo, query, Y);
    ln_kernel<<<1024, 256, 0, stream>>>(Y, gamma, beta, out);
}

// Round 8
// 443.303 us; speedup vs baseline: 1.1004x; 1.0144x over previous
//
#include <hip/hip_runtime.h>

#define B_ 2
#define S_ 2048
#define D_ 512
#define H_ 8
#define DH_ 64

typedef __bf16 bf16_8 __attribute__((ext_vector_type(8)));
typedef float f32x4 __attribute__((ext_vector_type(4)));
typedef unsigned int u32x4 __attribute__((ext_vector_type(4)));

union BfPack4 { ushort4 u; __bf16 h[4]; };

// ---------------------------------------------------------------------------
// Kernel 1: QKV projection.  y = x @ W^T  (torch Linear), bf16 outputs.
// z=0: Q (scaled by 1/8), z=1: K, z=2: V stored transposed [B,H,DH,S].
// ---------------------------------------------------------------------------
__global__ __launch_bounds__(256) void proj_qkv(
    const float* __restrict__ Xq, const float* __restrict__ Xk, const float* __restrict__ Xv,
    const float* __restrict__ Wq, const float* __restrict__ Wk, const float* __restrict__ Wv,
    __bf16* __restrict__ Qb, __bf16* __restrict__ Kb, __bf16* __restrict__ Vt)
{
    const int z = blockIdx.z;
    const float* X = (z == 0) ? Xq : (z == 1) ? Xk : Xv;
    const float* W = (z == 0) ? Wq : (z == 1) ? Wk : Wv;
    const int m0 = blockIdx.x * 64;   // 0..4095
    const int n0 = blockIdx.y * 64;   // 0..511

    __shared__ __bf16 Xs[64][72];
    __shared__ __bf16 Ws[64][72];

    const int tid = threadIdx.x;
    const int w = tid >> 6, lane = tid & 63;
    const int quad = lane >> 4, mc = lane & 15;

    int rr[4], cc[4];
    for (int i = 0; i < 4; ++i) { int e = tid + i * 256; rr[i] = e >> 4; cc[i] = (e & 15) * 4; }

    f32x4 acc[4] = {};
    float4 xr[4], wv[4];
    for (int i = 0; i < 4; ++i) {
        xr[i] = *reinterpret_cast<const float4*>(&X[(size_t)(m0 + rr[i]) * 512 + cc[i]]);
        wv[i] = *reinterpret_cast<const float4*>(&W[(size_t)(n0 + rr[i]) * 512 + cc[i]]);
    }

    for (int kc = 0; kc < 512; kc += 64) {
        if (kc) __syncthreads();
        for (int i = 0; i < 4; ++i) {
            BfPack4 px, pw;
            px.h[0] = (__bf16)xr[i].x; px.h[1] = (__bf16)xr[i].y;
            px.h[2] = (__bf16)xr[i].z; px.h[3] = (__bf16)xr[i].w;
            *reinterpret_cast<ushort4*>(&Xs[rr[i]][cc[i]]) = px.u;
            pw.h[0] = (__bf16)wv[i].x; pw.h[1] = (__bf16)wv[i].y;
            pw.h[2] = (__bf16)wv[i].z; pw.h[3] = (__bf16)wv[i].w;
            *reinterpret_cast<ushort4*>(&Ws[rr[i]][cc[i]]) = pw.u;
        }
        __syncthreads();
        if (kc < 448) {
            for (int i = 0; i < 4; ++i) {
                xr[i] = *reinterpret_cast<const float4*>(&X[(size_t)(m0 + rr[i]) * 512 + kc + 64 + cc[i]]);
                wv[i] = *reinterpret_cast<const float4*>(&W[(size_t)(n0 + rr[i]) * 512 + kc + 64 + cc[i]]);
            }
        }
        for (int ks = 0; ks < 64; ks += 32) {
            bf16_8 a = *reinterpret_cast<const bf16_8*>(&Xs[w * 16 + mc][ks + quad * 8]);
            for (int tt = 0; tt < 4; ++tt) {
                bf16_8 bb = *reinterpret_cast<const bf16_8*>(&Ws[tt * 16 + mc][ks + quad * 8]);
                acc[tt] = __builtin_amdgcn_mfma_f32_16x16x32_bf16(a, bb, acc[tt], 0, 0, 0);
            }
        }
    }
    __syncthreads();
    const float scale = (z == 0) ? 0.125f : 1.0f;   // DH^-0.5 folded into Q
    if (z < 2) {
        for (int tt = 0; tt < 4; ++tt)
            for (int r = 0; r < 4; ++r)
                Xs[w * 16 + quad * 4 + r][tt * 16 + mc] = (__bf16)(acc[tt][r] * scale);
    } else {
        for (int tt = 0; tt < 4; ++tt)
            for (int r = 0; r < 4; ++r)
                Xs[tt * 16 + mc][w * 16 + quad * 4 + r] = (__bf16)acc[tt][r];  // transposed tile [dh][s]
    }
    __syncthreads();
    if (z < 2) {
        __bf16* out = (z == 0) ? Qb : Kb;
        for (int i = 0; i < 2; ++i) {
            int e = tid + i * 256;
            int r = e >> 3, c8 = (e & 7) * 8;
            *reinterpret_cast<uint4*>(&out[(size_t)(m0 + r) * 512 + n0 + c8]) =
                *reinterpret_cast<const uint4*>(&Xs[r][c8]);
        }
    } else {
        int b = m0 >> 11, s0 = m0 & 2047, h = n0 >> 6;
        for (int i = 0; i < 2; ++i) {
            int e = tid + i * 256;
            int r = e >> 3, c8 = (e & 7) * 8;   // r = dh, c8 = s offset
            *reinterpret_cast<uint4*>(&Vt[(((size_t)(b * H_ + h)) * DH_ + r) * S_ + s0 + c8]) =
                *reinterpret_cast<const uint4*>(&Xs[r][c8]);
        }
    }
}

// ---------------------------------------------------------------------------
// Kernel 2: single-pass attention, 8 waves/WG, SWAPPED QK^T (T12 trick).
// Wave kg owns k-cols [kg*256,+256), 4 chunks of 64. Computing mfma(K, Q)
// instead of mfma(Q, K) transposes the C-tile so each lane holds P values
// for ITS OWN q-row (mc) with k consecutive per tt:
//   - P-stash becomes 4x packed 8B ds_write_b64 (was 16x ds_write_b16)
//   - l is a lane-local scalar; reduction = 2 shuffles (was 16)
// Dot products are bitwise identical (same MFMA contraction, transposed
// placement). PV and all epilogues unchanged from the passing round-7 form.
// s_setprio(1) around MFMA clusters (helps independent-wave attn, m191).
// LDS ~67 KB -> 2 WG/CU = 16 waves/CU; ~117 VGPR under (512,4) cap 128.
// ---------------------------------------------------------------------------
__global__ __launch_bounds__(512, 4) void attn_kernel(
    const __bf16* __restrict__ Qb, const __bf16* __restrict__ Kb, const __bf16* __restrict__ Vt,
    __bf16* __restrict__ Ctx, float* __restrict__ attn_out)
{
    const int qt = blockIdx.x;        // 0..127 (16-row q tiles)
    const int bh = blockIdx.y;        // 0..15
    const int b = bh >> 3, h = bh & 7;
    const int q0 = qt * 16;

    // PsW: [8 waves][16 rows][264 cols] bf16 = 67584 B; Osc overlays after.
    __shared__ __align__(16) char smem[8 * 16 * 264 * 2];
    __shared__ float Lsh[8][16];
    __shared__ float linv_s[16];

    const int tid = threadIdx.x;
    const int kg = tid >> 6, lane = tid & 63;
    const int quad = lane >> 4, mc = lane & 15;

    __bf16* PsW = reinterpret_cast<__bf16*>(smem) + kg * 16 * 264;

    // Q fragments straight from global (row = mc, dh split in two halves)
    const __bf16* qrow = &Qb[((size_t)b * S_ + q0 + mc) * D_ + h * DH_];
    const bf16_8 aq0 = *reinterpret_cast<const bf16_8*>(&qrow[quad * 8]);
    const bf16_8 aq1 = *reinterpret_cast<const bf16_8*>(&qrow[32 + quad * 8]);

    const __bf16* kbase = Kb + ((size_t)b * S_ + kg * 256) * D_ + h * DH_;
    const __bf16* vbase = Vt + (size_t)bh * DH_ * S_ + kg * 256;

    float l = 0.f;                    // denominator partial for q-row mc
    f32x4 o[4] = {};
    bf16_8 kb[8], vb[8];

    auto loadK = [&](int c) {
        for (int tt = 0; tt < 4; ++tt) {
            const __bf16* kr = &kbase[(size_t)(c * 64 + tt * 16 + mc) * D_];
            kb[tt]     = *reinterpret_cast<const bf16_8*>(&kr[quad * 8]);
            kb[4 + tt] = *reinterpret_cast<const bf16_8*>(&kr[32 + quad * 8]);
        }
    };
    auto loadV = [&](int c) {
        for (int ks2 = 0; ks2 < 2; ++ks2)
            for (int tt = 0; tt < 4; ++tt)
                vb[ks2 * 4 + tt] = *reinterpret_cast<const bf16_8*>(
                    &vbase[(size_t)(tt * 16 + mc) * S_ + c * 64 + ks2 * 32 + quad * 8]);
    };

    loadK(0);
    loadV(0);
#pragma unroll
    for (int c = 0; c < 4; ++c) {
        // ---- QK chunk c, SWAPPED: s[tt] = C[k-local][q-row] ----
        f32x4 s[4] = {};
        __builtin_amdgcn_s_setprio(1);
        for (int tt = 0; tt < 4; ++tt)
            s[tt] = __builtin_amdgcn_mfma_f32_16x16x32_bf16(kb[tt], aq0, s[tt], 0, 0, 0);
        for (int tt = 0; tt < 4; ++tt)
            s[tt] = __builtin_amdgcn_mfma_f32_16x16x32_bf16(kb[4 + tt], aq1, s[tt], 0, 0, 0);
        __builtin_amdgcn_s_setprio(0);
        // ---- p = exp(s): lane owns q-row mc, k = c*64 + tt*16 + quad*4 + r
        //      -> 4 consecutive bf16 per tt = one packed 8B LDS write ----
        for (int tt = 0; tt < 4; ++tt) {
            BfPack4 pk;
            for (int r = 0; r < 4; ++r) {
                float p = __expf(s[tt][r]);
                l += p;
                pk.h[r] = (__bf16)p;
            }
            *reinterpret_cast<ushort4*>(
                &PsW[mc * 264 + c * 64 + tt * 16 + quad * 4]) = pk.u;
        }
        // ---- prefetch next K (kb dead after QK) ----
        if (c < 3) loadK(c + 1);
        // ---- PV chunk c: A = PsW row mc (unchanged layout) ----
        __builtin_amdgcn_s_setprio(1);
        for (int ks2 = 0; ks2 < 2; ++ks2) {
            bf16_8 ap = *reinterpret_cast<const bf16_8*>(
                &PsW[mc * 264 + c * 64 + ks2 * 32 + quad * 8]);
            for (int tt = 0; tt < 4; ++tt)
                o[tt] = __builtin_amdgcn_mfma_f32_16x16x32_bf16(ap, vb[ks2 * 4 + tt], o[tt], 0, 0, 0);
        }
        __builtin_amdgcn_s_setprio(0);
        // ---- prefetch next V (vb dead after PV) ----
        if (c < 3) loadV(c + 1);
    }

    // ---- combine l: lanes sharing mc (xor 16, 32), then across 8 waves ----
    l += __shfl_xor(l, 16);
    l += __shfl_xor(l, 32);
    if (lane < 16) Lsh[kg][lane] = l;
    __syncthreads();
    if (tid < 16) {
        float t = 0.f;
        for (int g = 0; g < 8; ++g) t += Lsh[g][tid];
        linv_s[tid] = 1.f / t;
    }
    __syncthreads();

    // ---- normalized attention write: wave kg covers cols [kg*256, +256) ----
    for (int r = 0; r < 16; ++r) {
        const float li = linv_s[r];
        BfPack4 pu;
        pu.u = *reinterpret_cast<const ushort4*>(&PsW[r * 264 + lane * 4]);
        f32x4 ov;
        for (int j = 0; j < 4; ++j) ov[j] = (float)pu.h[j] * li;
        __builtin_nontemporal_store(ov, reinterpret_cast<f32x4*>(
            &attn_out[((size_t)bh * S_ + q0 + r) * S_ + kg * 256 + lane * 4]));
    }
    __syncthreads();   // all Ps reads done -> smem reusable as Osc

    // ---- combine PV partials via overlay, write Ctx normalized bf16 ----
    // o layout: C[q-row quad*4+j][dh tt*16+mc] (PV operands unchanged)
    float* Osc = reinterpret_cast<float*>(smem);   // [8][16][68] f32 = 34816 B
    for (int tt = 0; tt < 4; ++tt)
        for (int j = 0; j < 4; ++j)
            Osc[(kg * 16 + quad * 4 + j) * 68 + tt * 16 + mc] = o[tt][j];
    __syncthreads();
    if (tid < 256) {
        const int row = tid >> 4;          // 0..15
        const int dhg = (tid & 15) * 4;    // 0..60
        const float li = linv_s[row];
        BfPack4 pk;
        for (int kk = 0; kk < 4; ++kk) {
            float v = 0.f;
            for (int g = 0; g < 8; ++g)
                v += Osc[(g * 16 + row) * 68 + dhg + kk];
            pk.h[kk] = (__bf16)(v * li);
        }
        *reinterpret_cast<ushort4*>(&Ctx[((size_t)b * S_ + q0 + row) * D_ + h * DH_ + dhg]) = pk.u;
    }
}

// ---------------------------------------------------------------------------
// Kernel 3a: output projection + bias + residual -> fp32 ws
// ---------------------------------------------------------------------------
__global__ __launch_bounds__(256) void oproj(
    const __bf16* __restrict__ Ctx, const float* __restrict__ Wo,
    const float* __restrict__ bo, const float* __restrict__ resid,
    float* __restrict__ Y)
{
    const int m0 = blockIdx.x * 64;
    const int n0 = blockIdx.y * 64;

    __shared__ __bf16 As[64][72];
    __shared__ __bf16 Bs[64][72];

    const int tid = threadIdx.x;
    const int w = tid >> 6, lane = tid & 63;
    const int quad = lane >> 4, mc = lane & 15;

    int ar[2], ac[2], wr2[4], wc2[4];
    for (int i = 0; i < 2; ++i) { int e = tid + i * 256; ar[i] = e >> 3; ac[i] = (e & 7) * 8; }
    for (int i = 0; i < 4; ++i) { int e = tid + i * 256; wr2[i] = e >> 4; wc2[i] = (e & 15) * 4; }

    uint4 areg[2];
    float4 wreg[4];
    for (int i = 0; i < 2; ++i)
        areg[i] = *reinterpret_cast<const uint4*>(&Ctx[(size_t)(m0 + ar[i]) * 512 + ac[i]]);
    for (int i = 0; i < 4; ++i)
        wreg[i] = *reinterpret_cast<const float4*>(&Wo[(size_t)(n0 + wr2[i]) * 512 + wc2[i]]);

    f32x4 acc[4] = {};
    for (int kc = 0; kc < 512; kc += 64) {
        if (kc) __syncthreads();
        for (int i = 0; i < 2; ++i)
            *reinterpret_cast<uint4*>(&As[ar[i]][ac[i]]) = areg[i];
        for (int i = 0; i < 4; ++i) {
            BfPack4 pw;
            pw.h[0] = (__bf16)wreg[i].x; pw.h[1] = (__bf16)wreg[i].y;
            pw.h[2] = (__bf16)wreg[i].z; pw.h[3] = (__bf16)wreg[i].w;
            *reinterpret_cast<ushort4*>(&Bs[wr2[i]][wc2[i]]) = pw.u;
        }
        __syncthreads();
        if (kc < 448) {
            for (int i = 0; i < 2; ++i)
                areg[i] = *reinterpret_cast<const uint4*>(&Ctx[(size_t)(m0 + ar[i]) * 512 + kc + 64 + ac[i]]);
            for (int i = 0; i < 4; ++i)
                wreg[i] = *reinterpret_cast<const float4*>(&Wo[(size_t)(n0 + wr2[i]) * 512 + kc + 64 + wc2[i]]);
        }
        for (int ks = 0; ks < 64; ks += 32) {
            bf16_8 a = *reinterpret_cast<const bf16_8*>(&As[w * 16 + mc][ks + quad * 8]);
            for (int tt = 0; tt < 4; ++tt) {
                bf16_8 bb = *reinterpret_cast<const bf16_8*>(&Bs[tt * 16 + mc][ks + quad * 8]);
                acc[tt] = __builtin_amdgcn_mfma_f32_16x16x32_bf16(a, bb, acc[tt], 0, 0, 0);
            }
        }
    }
    for (int tt = 0; tt < 4; ++tt) {
        int col = n0 + tt * 16 + mc;
        float bias = bo[col];
        for (int r = 0; r < 4; ++r) {
            int row = m0 + w * 16 + quad * 4 + r;
            Y[(size_t)row * 512 + col] = acc[tt][r] + bias + resid[(size_t)row * 512 + col];
        }
    }
}

// ---------------------------------------------------------------------------
// Kernel 3b: LayerNorm over last dim (512). One wave per row.
// ---------------------------------------------------------------------------
__global__ __launch_bounds__(256) void ln_kernel(
    const float* __restrict__ Y, const float* __restrict__ gamma,
    const float* __restrict__ beta, float* __restrict__ out)
{
    const int row = blockIdx.x * 4 + (threadIdx.x >> 6);
    const int lane = threadIdx.x & 63;
    const float* y = &Y[(size_t)row * 512];
    float4 v0 = *reinterpret_cast<const float4*>(&y[lane * 8]);
    float4 v1 = *reinterpret_cast<const float4*>(&y[lane * 8 + 4]);
    float sum = v0.x + v0.y + v0.z + v0.w + v1.x + v1.y + v1.z + v1.w;
    float sq = v0.x * v0.x + v0.y * v0.y + v0.z * v0.z + v0.w * v0.w +
               v1.x * v1.x + v1.y * v1.y + v1.z * v1.z + v1.w * v1.w;
    for (int off = 1; off < 64; off <<= 1) {
        sum += __shfl_xor(sum, off);
        sq  += __shfl_xor(sq, off);
    }
    const float mean = sum * (1.f / 512.f);
    const float var = sq * (1.f / 512.f) - mean * mean;
    const float rstd = rsqrtf(var + 1e-5f);
    float4 g0 = *reinterpret_cast<const float4*>(&gamma[lane * 8]);
    float4 g1 = *reinterpret_cast<const float4*>(&gamma[lane * 8 + 4]);
    float4 b0 = *reinterpret_cast<const float4*>(&beta[lane * 8]);
    float4 b1 = *reinterpret_cast<const float4*>(&beta[lane * 8 + 4]);
    float4 o0, o1;
    o0.x = (v0.x - mean) * rstd * g0.x + b0.x;
    o0.y = (v0.y - mean) * rstd * g0.y + b0.y;
    o0.z = (v0.z - mean) * rstd * g0.z + b0.z;
    o0.w = (v0.w - mean) * rstd * g0.w + b0.w;
    o1.x = (v1.x - mean) * rstd * g1.x + b1.x;
    o1.y = (v1.y - mean) * rstd * g1.y + b1.y;
    o1.z = (v1.z - mean) * rstd * g1.z + b1.z;
    o1.w = (v1.w - mean) * rstd * g1.w + b1.w;
    *reinterpret_cast<float4*>(&out[(size_t)row * 512 + lane * 8]) = o0;
    *reinterpret_cast<float4*>(&out[(size_t)row * 512 + lane * 8 + 4]) = o1;
}

// ---------------------------------------------------------------------------
extern "C" void kernel_launch(void* const* d_in, const int* in_sizes, int n_in,
                              void* d_out, int out_size, void* d_ws, size_t ws_size,
                              hipStream_t stream)
{
    const float* query = (const float*)d_in[0];
    const float* key   = (const float*)d_in[1];
    const float* value = (const float*)d_in[2];
    const float* Wq    = (const float*)d_in[3];
    const float* Wk    = (const float*)d_in[4];
    const float* Wv    = (const float*)d_in[5];
    const float* Wo    = (const float*)d_in[6];
    const float* bo    = (const float*)d_in[7];
    const float* gamma = (const float*)d_in[8];
    const float* beta  = (const float*)d_in[9];

    float* out = (float*)d_out;                       // [output | attention]
    float* attn_out = out + (size_t)B_ * S_ * D_;     // offset 2*2048*512

    char* ws = (char*)d_ws;
    __bf16* Qb  = (__bf16*)(ws);                      // 4 MB, [B,S,D] bf16, pre-scaled
    __bf16* Kb  = (__bf16*)(ws + (4u << 20));         // 4 MB, [B,S,D]
    __bf16* Vt  = (__bf16*)(ws + (8u << 20));         // 4 MB, [B,H,DH,S]
    __bf16* Ctx = (__bf16*)(ws + (12u << 20));        // 4 MB, [B,S,D]
    float*  Y   = (float*)(ws + (16u << 20));         // 8 MB fp32

    proj_qkv<<<dim3(64, 8, 3), 256, 0, stream>>>(query, key, value, Wq, Wk, Wv, Qb, Kb, Vt);
    attn_kernel<<<dim3(128, 16), 512, 0, stream>>>(Qb, Kb, Vt, Ctx, attn_out);
    oproj<<<dim3(64, 8), 256, 0, stream>>>(Ctx, Wo, bo, query, Y);
    ln_kernel<<<1024, 256, 0, stream>>>(Y, gamma, beta, out);
}